// Round 12
// baseline (192.424 us; speedup 1.0000x reference)
//
#include <hip/hip_runtime.h>
#include <hip/hip_bf16.h>
#include <stdint.h>
#include <stddef.h>

typedef short s8v __attribute__((ext_vector_type(8)));   // 8 bf16 bit patterns
typedef short s4v __attribute__((ext_vector_type(4)));   // 4 bf16 bit patterns
typedef float f4v __attribute__((ext_vector_type(4)));

__device__ inline float b2f(short s) {
    union { unsigned u; float f; } x;
    x.u = ((unsigned)(unsigned short)s) << 16;
    return x.f;
}
__device__ inline short f2b(float f) {
    union { float f; unsigned u; } x;
    x.f = f;
    unsigned r = x.u + 0x7FFF + ((x.u >> 16) & 1);  // round-to-nearest-even
    return (short)(r >> 16);
}

// async global(16B/lane) -> LDS; dst must be wave-uniform base (HW adds lane*16)
__device__ __forceinline__ void gl16(const short* g, short* l) {
    __builtin_amdgcn_global_load_lds(
        (const __attribute__((address_space(1))) void*)g,
        (__attribute__((address_space(3))) void*)l,
        16, 0, 0);
}

// ---------------------------------------------------------------------------
// Convert 5 arrays to bf16 (fp32 inputs detected per-wave from x[0..1023]).
// Block 0 publishes the flag for the proj epilogue.
// ---------------------------------------------------------------------------
__global__ __launch_bounds__(256) void convert_bf16(
    const void* s0, short* d0, size_t c0,
    const void* s1, short* d1, size_t c1,
    const void* s2, short* d2, size_t c2,
    const void* s3, short* d3, size_t c3,
    const void* s4, short* d4, size_t c4,
    int* __restrict__ flagout)
{
    int hit = 0;
    const unsigned* xw = (const unsigned*)s0;
    for (int i = threadIdx.x & 63; i < 1024; i += 64) {
        unsigned e = ((xw[i] & 0xFFFFu) >> 7) & 0xFFu;
        if (e >= 0x8Au) hit = 1;
    }
    const bool f32 = (__ballot(hit != 0) != 0ull);
    if (blockIdx.x == 0 && threadIdx.x == 0) *flagout = f32 ? 1 : 0;

    const void* srcs[5] = {s0, s1, s2, s3, s4};
    short* dsts[5] = {d0, d1, d2, d3, d4};
    size_t cnts[5] = {c0, c1, c2, c3, c4};
    size_t total = c0 + c1 + c2 + c3 + c4;
    size_t stride = (size_t)gridDim.x * blockDim.x;
    for (size_t c = (size_t)blockIdx.x * blockDim.x + threadIdx.x; c < total; c += stride) {
        size_t r = c; int s = 0;
        while (r >= cnts[s]) { r -= cnts[s]; s++; }
        short* d = dsts[s] + r * 8;
        if (f32) {
            const float* p = (const float*)srcs[s] + r * 8;
            f4v a = *(const f4v*)p;
            f4v b = *(const f4v*)(p + 4);
            s8v v;
            v[0] = f2b(a[0]); v[1] = f2b(a[1]); v[2] = f2b(a[2]); v[3] = f2b(a[3]);
            v[4] = f2b(b[0]); v[5] = f2b(b[1]); v[6] = f2b(b[2]); v[7] = f2b(b[3]);
            *(s8v*)d = v;
        } else {
            *(s8v*)d = *(const s8v*)((const short*)srcs[s] + r * 8);
        }
    }
}

// ---------------------------------------------------------------------------
// C[M,N] = A[M,K] @ B[N,K]^T + bias[N]; all-bf16, global_load_lds staging.
// Tile TBM x TBN, 4 waves (2x2), wave tile (TBM/2)x(TBN/2).
// T1: XCD-aware bijective block swizzle (grid % 8 == 0 required).
// QKV=1 (TBM=TBN=128): V transposed per head into vT; Q/K repacked via LDS.
// Epilogues in two 64-row halves (R6 config — single-pass measured slower).
// NOTE: keeps __syncthreads (gl16's LDS landing is vmcnt-tracked; the
// vmcnt(0) drain before barrier is REQUIRED for cross-wave visibility).
// ---------------------------------------------------------------------------
#define BKK 64

template<int QKV, int TBM, int TBN, int MINW>
__global__ __launch_bounds__(256, MINW) void gemm_bt_bias(
    const short* __restrict__ A,      // [M,K] bf16
    const short* __restrict__ B,      // [N,K] bf16
    const short* __restrict__ bias,   // [N]   bf16
    void* __restrict__ C,             // [M,ldc]
    short* __restrict__ vT,           // [B*H,64,2048] when QKV
    int M, int N, int K, int ldc,
    const int* __restrict__ flagp, int oDyn)
{
    const bool of32 = oDyn && (*flagp != 0);
    const int MT = TBM / 32, NT = TBN / 32;

    __shared__ __align__(16) short smem[(TBM + TBN) * BKK];
    short* sA = smem;
    short* sB = smem + TBM * BKK;

    const int tid  = threadIdx.x;
    const int lane = tid & 63;
    const int w    = tid >> 6;
    const int wm   = (w >> 1) * (TBM / 2);
    const int wn   = (w & 1) * (TBN / 2);
    const int quad = lane >> 4;
    const int l16  = lane & 15;

    // T1 XCD swizzle: HW round-robins consecutive flat blockIdx across XCDs;
    // give each XCD a contiguous logical chunk (A-panel + B-panel L2 reuse).
    const int bid0 = blockIdx.y * (int)gridDim.x + blockIdx.x;
    const int nwg  = (int)(gridDim.x * gridDim.y);
    const int lb   = (bid0 & 7) * (nwg >> 3) + (bid0 >> 3);
    const int m0 = (lb / (int)gridDim.x) * TBM;
    const int n0 = (lb % (int)gridDim.x) * TBN;

    f4v acc[MT][NT];
    const f4v vzero = {0.0f, 0.0f, 0.0f, 0.0f};
#pragma unroll
    for (int i = 0; i < MT; i++)
#pragma unroll
        for (int j = 0; j < NT; j++) acc[i][j] = vzero;

    const int ACH = TBM * 8;               // A chunk count (multiple of 256)
    for (int k0 = 0; k0 < K; k0 += BKK) {
        __syncthreads();
#pragma unroll
        for (int i = 0; i < (TBM + TBN) / 32; i++) {
            int c  = i * 256 + tid;
            int cb = i * 256 + (tid & 192);        // wave-uniform chunk base
            if (c < ACH) {
                int r = c >> 3, kk = (c & 7) * 8;
                gl16(A + (size_t)(m0 + r) * K + k0 + kk, sA + cb * 8);
            } else {
                int c2 = c - ACH, cb2 = cb - ACH;
                int r = c2 >> 3, kk = (c2 & 7) * 8;
                gl16(B + (size_t)(n0 + r) * K + k0 + kk, sB + cb2 * 8);
            }
        }
        __syncthreads();
#pragma unroll
        for (int s = 0; s < 2; s++) {
            s8v af[MT], bf[NT];
#pragma unroll
            for (int t = 0; t < MT; t++)
                af[t] = *(const s8v*)(sA + (wm + t * 16 + l16) * BKK + s * 32 + quad * 8);
#pragma unroll
            for (int t = 0; t < NT; t++)
                bf[t] = *(const s8v*)(sB + (wn + t * 16 + l16) * BKK + s * 32 + quad * 8);
#pragma unroll
            for (int mt = 0; mt < MT; mt++)
#pragma unroll
                for (int nt = 0; nt < NT; nt++)
                    acc[mt][nt] = __builtin_amdgcn_mfma_f32_16x16x32_bf16(
                        af[mt], bf[nt], acc[mt][nt], 0, 0, 0);
        }
    }

    // ---- epilogue: C/D layout col = lane&15, row = quad*4 + reg ----
    if (QKV && n0 >= 2048) {
        // V tile [128 m][128 n] -> vT[bh][d][t], two 64-row (m) halves.
        static_assert(!QKV || (TBM == 128 && TBN == 128), "V transpose assumes 128x128");
        const int bq = m0 >> 11;
#pragma unroll
        for (int hm = 0; hm < 2; hm++) {
            __syncthreads();
            if ((w >> 1) == hm) {
#pragma unroll
                for (int nt = 0; nt < NT; nt++) {
                    int nl = wn + nt * 16 + l16;
                    float bv = b2f(bias[n0 + nl]);
#pragma unroll
                    for (int mt = 0; mt < MT; mt++)
#pragma unroll
                        for (int r = 0; r < 4; r++) {
                            int ml2 = mt * 16 + quad * 4 + r;     // 0..63 within half
                            smem[nl * 72 + ml2] = f2b(acc[mt][nt][r] + bv);
                        }
                }
            }
            __syncthreads();
#pragma unroll
            for (int i = 0; i < 4; i++) {
                int c = i * 256 + tid;               // 0..1023
                int nl = c >> 3, col = (c & 7) * 8;  // 128 rows x 64 shorts
                int nn = n0 + nl;
                int hh = (nn - 2048) >> 6, d = nn & 63;
                short* dst = vT + (((size_t)(bq * 16 + hh)) * 64 + d) * 2048
                           + (m0 & 2047) + hm * 64 + col;
                *(s8v*)dst = *(const s8v*)(smem + nl * 72 + col);
            }
        }
    } else if (QKV) {
        // Q/K tile: LDS repack (stride 144) in two 64-row halves -> 16B stores
        const float osc = (n0 < 1024) ? 0.125f : 1.0f;   // exact Q prescale
#pragma unroll
        for (int hm = 0; hm < 2; hm++) {
            __syncthreads();
            if ((w >> 1) == hm) {
#pragma unroll
                for (int nt = 0; nt < NT; nt++) {
                    int nl = wn + nt * 16 + l16;
                    float bv = b2f(bias[n0 + nl]);
#pragma unroll
                    for (int mt = 0; mt < MT; mt++)
#pragma unroll
                        for (int r = 0; r < 4; r++) {
                            int ml2 = mt * 16 + quad * 4 + r;     // 0..63 within half
                            smem[ml2 * 144 + nl] = f2b((acc[mt][nt][r] + bv) * osc);
                        }
                }
            }
            __syncthreads();
#pragma unroll
            for (int i = 0; i < 4; i++) {
                int c = i * 256 + tid;              // 0..1023
                int m = c >> 4, ncol = (c & 15) * 8;
                *(s8v*)((short*)C + (size_t)(m0 + hm * 64 + m) * ldc + n0 + ncol) =
                    *(const s8v*)(smem + m * 144 + ncol);
            }
        }
    } else {
#pragma unroll
        for (int nt = 0; nt < NT; nt++) {
            int n = n0 + wn + nt * 16 + l16;
            float bv = b2f(bias[n]);
#pragma unroll
            for (int mt = 0; mt < MT; mt++) {
#pragma unroll
                for (int r = 0; r < 4; r++) {
                    int m = m0 + wm + mt * 16 + quad * 4 + r;
                    float v = acc[mt][nt][r] + bv;
                    if (of32) ((float*)C)[(size_t)m * ldc + n] = v;
                    else      ((short*)C)[(size_t)m * ldc + n] = f2b(v);
                }
            }
        }
    }
}

// ---------------------------------------------------------------------------
// Flash-style causal attention, BQ=64/block (wave=16 q-rows), no-rescale
// softmax (additive partials). PARTS=2: split-K over kt with bf16 O-partials
// + fp32 lsum partials; PARTS=1: direct y write.
// qk: [B*T,2048] bf16 (q prescaled by 1/8 | k), vT: [B*H,64,2048] bf16.
// R11 structure (2-deep T14 reg prefetch, T5 setprio, swapped QK^T) with
// RAW s_barrier instead of __syncthreads: attn reg-stages (no gl16), so
// cross-wave LDS visibility only needs lgkmcnt(0) on the ds_writes —
// __syncthreads' vmcnt(0) drain was retiring the 2-deep prefetch loads at
// every barrier. Raw barriers let prefetch genuinely span 2 tiles.
// sched_barrier(0) pins per guide rule #18. Barriers are block-uniform.
// ---------------------------------------------------------------------------
#define LP 72

template<int PARTS>
__global__ __launch_bounds__(256) void attn_flash(
    const short* __restrict__ qk,
    const short* __restrict__ vt,
    short* __restrict__ y,
    short* __restrict__ Opart,
    float* __restrict__ Lpart)
{
    const int T = 2048, LDQ = 2048;
    __shared__ __align__(16) short sK[64 * LP];
    __shared__ __align__(16) short sVT[64 * LP];
    __shared__ __align__(16) short sP[4][16 * LP];

    const int tid  = threadIdx.x;
    const int lane = tid & 63;
    const int w    = tid >> 6;
    const int quad = lane >> 4;
    const int l16  = lane & 15;

    int part, qt, bh, u;
    if (PARTS == 2) {
        part = blockIdx.x & 1;
        int rest = blockIdx.x >> 1;
        qt = 31 - (rest >> 5);           // LPT: long chunks first
        bh = rest & 31;
        u  = bh * 32 + qt;
    } else {
        part = 0;
        qt = 31 - (blockIdx.x >> 5);
        bh = blockIdx.x & 31;
        u  = 0;
    }
    const int b = bh >> 4;
    const int h = bh & 15;

    const int n    = qt + 1;
    const int half = (n + 1) >> 1;
    const int klo  = (PARTS == 2 && part) ? half : 0;
    const int khi  = (PARTS == 2 && !part) ? half : n;

    if (PARTS == 2 && klo >= khi) {       // empty chunk: zero partials
        s8v z;
#pragma unroll
        for (int j = 0; j < 8; j++) z[j] = 0;
        s8v* ob = (s8v*)(Opart + ((size_t)(part * 1024 + u)) * 4096);
        for (int i = tid; i < 512; i += 256) ob[i] = z;
        if (tid < 64) Lpart[(size_t)(part * 1024 + u) * 64 + tid] = 0.0f;
        return;
    }

    const size_t qkbase = (size_t)b * T * LDQ;
    const short* Kbase  = qk + qkbase + 1024 + h * 64;
    const short* Vbase  = vt + (size_t)bh * 64 * 2048;

    s8v qf[2];
    {
        int qrow = qt * 64 + w * 16 + l16;
        const short* qp = qk + qkbase + (size_t)qrow * LDQ + h * 64 + quad * 8;
        qf[0] = *(const s8v*)(qp);
        qf[1] = *(const s8v*)(qp + 32);
    }

    // staging geometry: per thread 2 K rows + 2 V rows, 16B each
    const int r0 = tid >> 3;             // 0..31
    const int dd = (tid & 7) * 8;        // 0..56

    const f4v vzero = {0.0f, 0.0f, 0.0f, 0.0f};
    f4v o[4];
#pragma unroll
    for (int i = 0; i < 4; i++) o[i] = vzero;
    float lsum = 0.0f;                   // per-lane partial for q = w*16+l16

    // 2-deep prologue: set A = tile klo, set B = tile klo+1 (if any)
    s8v ka0, ka1, va0, va1, kb0, kb1, vb0, vb1;
    ka0 = *(const s8v*)(Kbase + (size_t)(klo * 64 + r0) * LDQ + dd);
    ka1 = *(const s8v*)(Kbase + (size_t)(klo * 64 + r0 + 32) * LDQ + dd);
    va0 = *(const s8v*)(Vbase + (size_t)r0 * 2048 + klo * 64 + dd);
    va1 = *(const s8v*)(Vbase + (size_t)(r0 + 32) * 2048 + klo * 64 + dd);
    if (klo + 1 < khi) {
        kb0 = *(const s8v*)(Kbase + (size_t)((klo + 1) * 64 + r0) * LDQ + dd);
        kb1 = *(const s8v*)(Kbase + (size_t)((klo + 1) * 64 + r0 + 32) * LDQ + dd);
        vb0 = *(const s8v*)(Vbase + (size_t)r0 * 2048 + (klo + 1) * 64 + dd);
        vb1 = *(const s8v*)(Vbase + (size_t)(r0 + 32) * 2048 + (klo + 1) * 64 + dd);
    }

    const int qg = w * 16 + l16;         // lane's q (local to the 64-block)

    // per-tile body: write reg set to LDS, refill it from tile kt+2, compute
    auto body = [&](s8v& kr0, s8v& kr1, s8v& vv0, s8v& vv1, int kt) {
        // (1) all waves done reading prev sK/sVT (their ds_reads were awaited
        // before their MFMAs, so reaching this barrier implies reads retired).
        // Raw barrier: does NOT drain vmcnt -> prefetch loads stay in flight.
        __builtin_amdgcn_s_barrier();
        __builtin_amdgcn_sched_barrier(0);
        *(s8v*)(sK  + r0 * LP + dd)        = kr0;
        *(s8v*)(sK  + (r0 + 32) * LP + dd) = kr1;
        *(s8v*)(sVT + r0 * LP + dd)        = vv0;
        *(s8v*)(sVT + (r0 + 32) * LP + dd) = vv1;
        if (kt + 2 < khi) {              // refill this set; flies 2 tiles
            kr0 = *(const s8v*)(Kbase + (size_t)((kt + 2) * 64 + r0) * LDQ + dd);
            kr1 = *(const s8v*)(Kbase + (size_t)((kt + 2) * 64 + r0 + 32) * LDQ + dd);
            vv0 = *(const s8v*)(Vbase + (size_t)r0 * 2048 + (kt + 2) * 64 + dd);
            vv1 = *(const s8v*)(Vbase + (size_t)(r0 + 32) * 2048 + (kt + 2) * 64 + dd);
        }
        // (2) LDS writes retired -> visible to other waves after barrier.
        asm volatile("s_waitcnt lgkmcnt(0)" ::: "memory");
        __builtin_amdgcn_sched_barrier(0);
        __builtin_amdgcn_s_barrier();
        __builtin_amdgcn_sched_barrier(0);

        // swapped QK^T: sacc = K·Q^T -> lane holds S[k=nt*16+quad*4+r][q=l16]
        f4v sacc[4];
        __builtin_amdgcn_s_setprio(1);   // T5: favor compute wave vs staging
#pragma unroll
        for (int nt = 0; nt < 4; nt++) {
            sacc[nt] = vzero;
            s8v kf0 = *(const s8v*)(sK + (nt * 16 + l16) * LP + quad * 8);
            s8v kf1 = *(const s8v*)(sK + (nt * 16 + l16) * LP + 32 + quad * 8);
            sacc[nt] = __builtin_amdgcn_mfma_f32_16x16x32_bf16(kf0, qf[0], sacc[nt], 0, 0, 0);
            sacc[nt] = __builtin_amdgcn_mfma_f32_16x16x32_bf16(kf1, qf[1], sacc[nt], 0, 0, 0);
        }
        __builtin_amdgcn_s_setprio(0);

        // P = exp(S); truncate to bf16, lsum accumulates truncated value.
        // 4 consecutive-k values per nt -> one packed ds_write_b64 each.
        short* pp = sP[w];
        const bool diag = (kt == qt);
#pragma unroll
        for (int nt = 0; nt < 4; nt++) {
            unsigned pu[4];
#pragma unroll
            for (int r = 0; r < 4; r++) {
                float p = __expf(sacc[nt][r]);
                if (diag) {
                    int k = nt * 16 + quad * 4 + r;
                    if (k > qg) p = 0.0f;
                }
                union { float f; unsigned u; } c2; c2.f = p;
                c2.u &= 0xFFFF0000u;
                pu[r] = c2.u;
                lsum += c2.f;
            }
            s4v pk;
            pk[0] = (short)(pu[0] >> 16); pk[1] = (short)(pu[1] >> 16);
            pk[2] = (short)(pu[2] >> 16); pk[3] = (short)(pu[3] >> 16);
            *(s4v*)(pp + l16 * LP + nt * 16 + quad * 4) = pk;
        }
        // sP[w] is wave-private: no block barrier needed before PV reads
        // (compiler inserts the lgkmcnt for this wave's own write->read dep)

        s8v pf0 = *(const s8v*)(pp + l16 * LP + quad * 8);
        s8v pf1 = *(const s8v*)(pp + l16 * LP + 32 + quad * 8);
        __builtin_amdgcn_s_setprio(1);   // T5: PV cluster
#pragma unroll
        for (int dt = 0; dt < 4; dt++) {
            s8v vf0 = *(const s8v*)(sVT + (dt * 16 + l16) * LP + quad * 8);
            s8v vf1 = *(const s8v*)(sVT + (dt * 16 + l16) * LP + 32 + quad * 8);
            o[dt] = __builtin_amdgcn_mfma_f32_16x16x32_bf16(pf0, vf0, o[dt], 0, 0, 0);
            o[dt] = __builtin_amdgcn_mfma_f32_16x16x32_bf16(pf1, vf1, o[dt], 0, 0, 0);
        }
        __builtin_amdgcn_s_setprio(0);
    };

    for (int kt = klo; kt < khi; kt += 2) {
        body(ka0, ka1, va0, va1, kt);
        if (kt + 1 < khi)
            body(kb0, kb1, vb0, vb1, kt + 1);
    }

    // reduce lsum over quad (lanes l16, l16+16, l16+32, l16+48)
    lsum += __shfl_xor(lsum, 16, 64);
    lsum += __shfl_xor(lsum, 32, 64);

    if (PARTS == 2) {
        short* ob = Opart + ((size_t)(part * 1024 + u)) * 4096;
#pragma unroll
        for (int dt = 0; dt < 4; dt++)
#pragma unroll
            for (int r = 0; r < 4; r++)
                ob[(w * 16 + quad * 4 + r) * 64 + dt * 16 + l16] = f2b(o[dt][r]);
        if (lane < 16)
            Lpart[(size_t)(part * 1024 + u) * 64 + w * 16 + lane] = lsum;
    } else {
        float rls[4];
#pragma unroll
        for (int r = 0; r < 4; r++)
            rls[r] = 1.0f / __shfl(lsum, quad * 4 + r, 64);
#pragma unroll
        for (int dt = 0; dt < 4; dt++)
#pragma unroll
            for (int r = 0; r < 4; r++) {
                int qrow = qt * 64 + w * 16 + quad * 4 + r;
                int d = dt * 16 + l16;
                y[((size_t)b * T + qrow) * 1024 + h * 64 + d] = f2b(o[dt][r] * rls[r]);
            }
    }
}

// ---------------------------------------------------------------------------
// Combine split-K partials: y = (O0 + O1) / (l0 + l1). 1024 blocks x 256.
// ---------------------------------------------------------------------------
__global__ __launch_bounds__(256) void attn_combine(
    const short* __restrict__ Opart,
    const float* __restrict__ Lpart,
    short* __restrict__ y)
{
    const int u  = blockIdx.x;           // u = bh*32 + qt
    const int bh = u >> 5, qt = u & 31;
    const int b = bh >> 4, h = bh & 15;
    const int t = threadIdx.x;
    const int q = t >> 2, dg = (t & 3) * 16;

    float l = Lpart[(size_t)u * 64 + q] + Lpart[(size_t)(1024 + u) * 64 + q];
    float rl = 1.0f / l;
    const short* p0 = Opart + (size_t)u * 4096 + q * 64 + dg;
    const short* p1 = Opart + (size_t)(1024 + u) * 4096 + q * 64 + dg;
    short* yo = y + ((size_t)b * 2048 + qt * 64 + q) * 1024 + h * 64 + dg;
#pragma unroll
    for (int hv = 0; hv < 2; hv++) {
        s8v a = *(const s8v*)(p0 + hv * 8);
        s8v c = *(const s8v*)(p1 + hv * 8);
        s8v r;
#pragma unroll
        for (int j = 0; j < 8; j++) r[j] = f2b((b2f(a[j]) + b2f(c[j])) * rl);
        *(s8v*)(yo + hv * 8) = r;
    }
}

// ---------------------------------------------------------------------------
extern "C" void kernel_launch(void* const* d_in, const int* in_sizes, int n_in,
                              void* d_out, int out_size, void* d_ws, size_t ws_size,
                              hipStream_t stream)
{
    char* p = (char*)d_ws;
    int*   flag = (int*)p;                 p += 16;
    short* qk   = (short*)p;               p += (size_t)4096 * 2048 * 2;
    short* vT   = (short*)p;               p += (size_t)32 * 64 * 2048 * 2;
    short* xb   = (short*)p;               p += (size_t)4096 * 1024 * 2;
    short* Web  = (short*)p;               p += (size_t)3072 * 1024 * 2;
    short* Wpb  = (short*)p;               p += (size_t)1024 * 1024 * 2;
    short* beb  = (short*)p;               p += 3072 * 2;
    short* bpb  = (short*)p;               p += 1024 * 2;
    short* Opart = (short*)p;              p += (size_t)2 * 1024 * 4096 * 2;
    float* Lpart = (float*)p;              p += (size_t)2 * 1024 * 64 * 4;
    short* y = xb;                         // xb dead after QKV GEMM
    const size_t need = (size_t)(p - (char*)d_ws);
    const bool split = (ws_size >= need);

    // convert (self-detecting dtype; publishes flag for proj epilogue)
    convert_bf16<<<dim3(4098), 256, 0, stream>>>(
        d_in[0], xb,  (size_t)4096 * 1024 / 8,
        d_in[1], Web, (size_t)3072 * 1024 / 8,
        d_in[2], beb, (size_t)3072 / 8,
        d_in[3], Wpb, (size_t)1024 * 1024 / 8,
        d_in[4], bpb, (size_t)1024 / 8,
        flag);

    // qkv = x @ We^T + be ; Q (prescaled 1/8), K -> qk ; V -> vT transposed
    // 128x128 tiles, 768 blocks = 3/CU, T1 XCD swizzle
    gemm_bt_bias<1, 128, 128, 3><<<dim3(3072 / 128, 4096 / 128), 256, 0, stream>>>(
        xb, Web, beb, qk, vT, 4096, 3072, 1024, 2048, flag, 0);

    if (split) {
        attn_flash<2><<<dim3(2048), 256, 0, stream>>>(qk, vT, nullptr, Opart, Lpart);
        attn_combine<<<dim3(1024), 256, 0, stream>>>(Opart, Lpart, y);
    } else {
        attn_flash<1><<<dim3(1024), 256, 0, stream>>>(qk, vT, y, nullptr, nullptr);
    }

    // out = y @ Wp^T + bp ; 128x64 tiles, 512 blocks, T1 XCD swizzle
    gemm_bt_bias<0, 128, 64, 2><<<dim3(1024 / 64, 4096 / 128), 256, 0, stream>>>(
        y, Wpb, bpb, d_out, nullptr, 4096, 1024, 1024, 1024, flag, 1);
}

// Round 13
// 188.885 us; speedup vs baseline: 1.0187x; 1.0187x over previous
//
#include <hip/hip_runtime.h>
#include <hip/hip_bf16.h>
#include <stdint.h>
#include <stddef.h>

typedef short s8v __attribute__((ext_vector_type(8)));   // 8 bf16 bit patterns
typedef short s4v __attribute__((ext_vector_type(4)));   // 4 bf16 bit patterns
typedef float f4v __attribute__((ext_vector_type(4)));

__device__ inline float b2f(short s) {
    union { unsigned u; float f; } x;
    x.u = ((unsigned)(unsigned short)s) << 16;
    return x.f;
}
__device__ inline short f2b(float f) {
    union { float f; unsigned u; } x;
    x.f = f;
    unsigned r = x.u + 0x7FFF + ((x.u >> 16) & 1);  // round-to-nearest-even
    return (short)(r >> 16);
}

// async global(16B/lane) -> LDS; dst must be wave-uniform base (HW adds lane*16)
__device__ __forceinline__ void gl16(const short* g, short* l) {
    __builtin_amdgcn_global_load_lds(
        (const __attribute__((address_space(1))) void*)g,
        (__attribute__((address_space(3))) void*)l,
        16, 0, 0);
}

// ---------------------------------------------------------------------------
// Convert 5 arrays to bf16 (fp32 inputs detected per-wave from x[0..1023]).
// Block 0 publishes the flag for the proj epilogue.
// ---------------------------------------------------------------------------
__global__ __launch_bounds__(256) void convert_bf16(
    const void* s0, short* d0, size_t c0,
    const void* s1, short* d1, size_t c1,
    const void* s2, short* d2, size_t c2,
    const void* s3, short* d3, size_t c3,
    const void* s4, short* d4, size_t c4,
    int* __restrict__ flagout)
{
    int hit = 0;
    const unsigned* xw = (const unsigned*)s0;
    for (int i = threadIdx.x & 63; i < 1024; i += 64) {
        unsigned e = ((xw[i] & 0xFFFFu) >> 7) & 0xFFu;
        if (e >= 0x8Au) hit = 1;
    }
    const bool f32 = (__ballot(hit != 0) != 0ull);
    if (blockIdx.x == 0 && threadIdx.x == 0) *flagout = f32 ? 1 : 0;

    const void* srcs[5] = {s0, s1, s2, s3, s4};
    short* dsts[5] = {d0, d1, d2, d3, d4};
    size_t cnts[5] = {c0, c1, c2, c3, c4};
    size_t total = c0 + c1 + c2 + c3 + c4;
    size_t stride = (size_t)gridDim.x * blockDim.x;
    for (size_t c = (size_t)blockIdx.x * blockDim.x + threadIdx.x; c < total; c += stride) {
        size_t r = c; int s = 0;
        while (r >= cnts[s]) { r -= cnts[s]; s++; }
        short* d = dsts[s] + r * 8;
        if (f32) {
            const float* p = (const float*)srcs[s] + r * 8;
            f4v a = *(const f4v*)p;
            f4v b = *(const f4v*)(p + 4);
            s8v v;
            v[0] = f2b(a[0]); v[1] = f2b(a[1]); v[2] = f2b(a[2]); v[3] = f2b(a[3]);
            v[4] = f2b(b[0]); v[5] = f2b(b[1]); v[6] = f2b(b[2]); v[7] = f2b(b[3]);
            *(s8v*)d = v;
        } else {
            *(s8v*)d = *(const s8v*)((const short*)srcs[s] + r * 8);
        }
    }
}

// ---------------------------------------------------------------------------
// C[M,N] = A[M,K] @ B[N,K]^T + bias[N]; all-bf16, global_load_lds staging.
// Tile TBM x TBN, 4 waves (2x2), wave tile (TBM/2)x(TBN/2).
// T1: XCD-aware bijective block swizzle (grid % 8 == 0 required).
// QKV=1 (TBM=TBN=128): V transposed per head into vT; Q/K repacked via LDS.
// Epilogues in two 64-row halves (R6 config — single-pass measured slower).
// Keeps __syncthreads: gl16's LDS landing is vmcnt-tracked, so the vmcnt(0)
// drain before barrier is REQUIRED for cross-wave visibility.
// ---------------------------------------------------------------------------
#define BKK 64

template<int QKV, int TBM, int TBN, int MINW>
__global__ __launch_bounds__(256, MINW) void gemm_bt_bias(
    const short* __restrict__ A,      // [M,K] bf16
    const short* __restrict__ B,      // [N,K] bf16
    const short* __restrict__ bias,   // [N]   bf16
    void* __restrict__ C,             // [M,ldc]
    short* __restrict__ vT,           // [B*H,64,2048] when QKV
    int M, int N, int K, int ldc,
    const int* __restrict__ flagp, int oDyn)
{
    const bool of32 = oDyn && (*flagp != 0);
    const int MT = TBM / 32, NT = TBN / 32;

    __shared__ __align__(16) short smem[(TBM + TBN) * BKK];
    short* sA = smem;
    short* sB = smem + TBM * BKK;

    const int tid  = threadIdx.x;
    const int lane = tid & 63;
    const int w    = tid >> 6;
    const int wm   = (w >> 1) * (TBM / 2);
    const int wn   = (w & 1) * (TBN / 2);
    const int quad = lane >> 4;
    const int l16  = lane & 15;

    // T1 XCD swizzle: HW round-robins consecutive flat blockIdx across XCDs;
    // give each XCD a contiguous logical chunk (A-panel + B-panel L2 reuse).
    const int bid0 = blockIdx.y * (int)gridDim.x + blockIdx.x;
    const int nwg  = (int)(gridDim.x * gridDim.y);
    const int lb   = (bid0 & 7) * (nwg >> 3) + (bid0 >> 3);
    const int m0 = (lb / (int)gridDim.x) * TBM;
    const int n0 = (lb % (int)gridDim.x) * TBN;

    f4v acc[MT][NT];
    const f4v vzero = {0.0f, 0.0f, 0.0f, 0.0f};
#pragma unroll
    for (int i = 0; i < MT; i++)
#pragma unroll
        for (int j = 0; j < NT; j++) acc[i][j] = vzero;

    const int ACH = TBM * 8;               // A chunk count (multiple of 256)
    for (int k0 = 0; k0 < K; k0 += BKK) {
        __syncthreads();
#pragma unroll
        for (int i = 0; i < (TBM + TBN) / 32; i++) {
            int c  = i * 256 + tid;
            int cb = i * 256 + (tid & 192);        // wave-uniform chunk base
            if (c < ACH) {
                int r = c >> 3, kk = (c & 7) * 8;
                gl16(A + (size_t)(m0 + r) * K + k0 + kk, sA + cb * 8);
            } else {
                int c2 = c - ACH, cb2 = cb - ACH;
                int r = c2 >> 3, kk = (c2 & 7) * 8;
                gl16(B + (size_t)(n0 + r) * K + k0 + kk, sB + cb2 * 8);
            }
        }
        __syncthreads();
#pragma unroll
        for (int s = 0; s < 2; s++) {
            s8v af[MT], bf[NT];
#pragma unroll
            for (int t = 0; t < MT; t++)
                af[t] = *(const s8v*)(sA + (wm + t * 16 + l16) * BKK + s * 32 + quad * 8);
#pragma unroll
            for (int t = 0; t < NT; t++)
                bf[t] = *(const s8v*)(sB + (wn + t * 16 + l16) * BKK + s * 32 + quad * 8);
#pragma unroll
            for (int mt = 0; mt < MT; mt++)
#pragma unroll
                for (int nt = 0; nt < NT; nt++)
                    acc[mt][nt] = __builtin_amdgcn_mfma_f32_16x16x32_bf16(
                        af[mt], bf[nt], acc[mt][nt], 0, 0, 0);
        }
    }

    // ---- epilogue: C/D layout col = lane&15, row = quad*4 + reg ----
    if (QKV && n0 >= 2048) {
        // V tile [128 m][128 n] -> vT[bh][d][t], two 64-row (m) halves.
        static_assert(!QKV || (TBM == 128 && TBN == 128), "V transpose assumes 128x128");
        const int bq = m0 >> 11;
#pragma unroll
        for (int hm = 0; hm < 2; hm++) {
            __syncthreads();
            if ((w >> 1) == hm) {
#pragma unroll
                for (int nt = 0; nt < NT; nt++) {
                    int nl = wn + nt * 16 + l16;
                    float bv = b2f(bias[n0 + nl]);
#pragma unroll
                    for (int mt = 0; mt < MT; mt++)
#pragma unroll
                        for (int r = 0; r < 4; r++) {
                            int ml2 = mt * 16 + quad * 4 + r;     // 0..63 within half
                            smem[nl * 72 + ml2] = f2b(acc[mt][nt][r] + bv);
                        }
                }
            }
            __syncthreads();
#pragma unroll
            for (int i = 0; i < 4; i++) {
                int c = i * 256 + tid;               // 0..1023
                int nl = c >> 3, col = (c & 7) * 8;  // 128 rows x 64 shorts
                int nn = n0 + nl;
                int hh = (nn - 2048) >> 6, d = nn & 63;
                short* dst = vT + (((size_t)(bq * 16 + hh)) * 64 + d) * 2048
                           + (m0 & 2047) + hm * 64 + col;
                *(s8v*)dst = *(const s8v*)(smem + nl * 72 + col);
            }
        }
    } else if (QKV) {
        // Q/K tile: LDS repack (stride 144) in two 64-row halves -> 16B stores
        const float osc = (n0 < 1024) ? 0.125f : 1.0f;   // exact Q prescale
#pragma unroll
        for (int hm = 0; hm < 2; hm++) {
            __syncthreads();
            if ((w >> 1) == hm) {
#pragma unroll
                for (int nt = 0; nt < NT; nt++) {
                    int nl = wn + nt * 16 + l16;
                    float bv = b2f(bias[n0 + nl]);
#pragma unroll
                    for (int mt = 0; mt < MT; mt++)
#pragma unroll
                        for (int r = 0; r < 4; r++) {
                            int ml2 = mt * 16 + quad * 4 + r;     // 0..63 within half
                            smem[ml2 * 144 + nl] = f2b((acc[mt][nt][r] + bv) * osc);
                        }
                }
            }
            __syncthreads();
#pragma unroll
            for (int i = 0; i < 4; i++) {
                int c = i * 256 + tid;              // 0..1023
                int m = c >> 4, ncol = (c & 15) * 8;
                *(s8v*)((short*)C + (size_t)(m0 + hm * 64 + m) * ldc + n0 + ncol) =
                    *(const s8v*)(smem + m * 144 + ncol);
            }
        }
    } else {
#pragma unroll
        for (int nt = 0; nt < NT; nt++) {
            int n = n0 + wn + nt * 16 + l16;
            float bv = b2f(bias[n]);
#pragma unroll
            for (int mt = 0; mt < MT; mt++) {
#pragma unroll
                for (int r = 0; r < 4; r++) {
                    int m = m0 + wm + mt * 16 + quad * 4 + r;
                    float v = acc[mt][nt][r] + bv;
                    if (of32) ((float*)C)[(size_t)m * ldc + n] = v;
                    else      ((short*)C)[(size_t)m * ldc + n] = f2b(v);
                }
            }
        }
    }
}

// ---------------------------------------------------------------------------
// Flash-style causal attention, BQ=64/block (wave=16 q-rows), no-rescale
// softmax (additive partials). PARTS=2: split-K over kt with bf16 O-partials
// + fp32 lsum partials; PARTS=1: direct y write.
// qk: [B*T,2048] bf16 (q prescaled by 1/8 | k), vT: [B*H,64,2048] bf16.
// R11 configuration (best measured): single LDS buffer, 2 barriers/tile
// via __syncthreads, 2-deep T14 register prefetch (named reg sets A/B,
// unroll-by-2), T5 setprio around MFMA clusters, swapped QK^T softmax
// (sacc = mfma(K,Q) -> lane owns 4 consecutive-k P values per nt ->
// packed ds_write_b64 P-store + scalar lsum with 2-shuffle reduce).
// sP is wave-private -> no barrier between softmax store and PV read.
// (R12's raw-barrier + sched_barrier pins regressed — m141 class.)
// ---------------------------------------------------------------------------
#define LP 72

template<int PARTS>
__global__ __launch_bounds__(256) void attn_flash(
    const short* __restrict__ qk,
    const short* __restrict__ vt,
    short* __restrict__ y,
    short* __restrict__ Opart,
    float* __restrict__ Lpart)
{
    const int T = 2048, LDQ = 2048;
    __shared__ __align__(16) short sK[64 * LP];
    __shared__ __align__(16) short sVT[64 * LP];
    __shared__ __align__(16) short sP[4][16 * LP];

    const int tid  = threadIdx.x;
    const int lane = tid & 63;
    const int w    = tid >> 6;
    const int quad = lane >> 4;
    const int l16  = lane & 15;

    int part, qt, bh, u;
    if (PARTS == 2) {
        part = blockIdx.x & 1;
        int rest = blockIdx.x >> 1;
        qt = 31 - (rest >> 5);           // LPT: long chunks first
        bh = rest & 31;
        u  = bh * 32 + qt;
    } else {
        part = 0;
        qt = 31 - (blockIdx.x >> 5);
        bh = blockIdx.x & 31;
        u  = 0;
    }
    const int b = bh >> 4;
    const int h = bh & 15;

    const int n    = qt + 1;
    const int half = (n + 1) >> 1;
    const int klo  = (PARTS == 2 && part) ? half : 0;
    const int khi  = (PARTS == 2 && !part) ? half : n;

    if (PARTS == 2 && klo >= khi) {       // empty chunk: zero partials
        s8v z;
#pragma unroll
        for (int j = 0; j < 8; j++) z[j] = 0;
        s8v* ob = (s8v*)(Opart + ((size_t)(part * 1024 + u)) * 4096);
        for (int i = tid; i < 512; i += 256) ob[i] = z;
        if (tid < 64) Lpart[(size_t)(part * 1024 + u) * 64 + tid] = 0.0f;
        return;
    }

    const size_t qkbase = (size_t)b * T * LDQ;
    const short* Kbase  = qk + qkbase + 1024 + h * 64;
    const short* Vbase  = vt + (size_t)bh * 64 * 2048;

    s8v qf[2];
    {
        int qrow = qt * 64 + w * 16 + l16;
        const short* qp = qk + qkbase + (size_t)qrow * LDQ + h * 64 + quad * 8;
        qf[0] = *(const s8v*)(qp);
        qf[1] = *(const s8v*)(qp + 32);
    }

    // staging geometry: per thread 2 K rows + 2 V rows, 16B each
    const int r0 = tid >> 3;             // 0..31
    const int dd = (tid & 7) * 8;        // 0..56

    const f4v vzero = {0.0f, 0.0f, 0.0f, 0.0f};
    f4v o[4];
#pragma unroll
    for (int i = 0; i < 4; i++) o[i] = vzero;
    float lsum = 0.0f;                   // per-lane partial for q = w*16+l16

    // 2-deep prologue: set A = tile klo, set B = tile klo+1 (if any)
    s8v ka0, ka1, va0, va1, kb0, kb1, vb0, vb1;
    ka0 = *(const s8v*)(Kbase + (size_t)(klo * 64 + r0) * LDQ + dd);
    ka1 = *(const s8v*)(Kbase + (size_t)(klo * 64 + r0 + 32) * LDQ + dd);
    va0 = *(const s8v*)(Vbase + (size_t)r0 * 2048 + klo * 64 + dd);
    va1 = *(const s8v*)(Vbase + (size_t)(r0 + 32) * 2048 + klo * 64 + dd);
    if (klo + 1 < khi) {
        kb0 = *(const s8v*)(Kbase + (size_t)((klo + 1) * 64 + r0) * LDQ + dd);
        kb1 = *(const s8v*)(Kbase + (size_t)((klo + 1) * 64 + r0 + 32) * LDQ + dd);
        vb0 = *(const s8v*)(Vbase + (size_t)r0 * 2048 + (klo + 1) * 64 + dd);
        vb1 = *(const s8v*)(Vbase + (size_t)(r0 + 32) * 2048 + (klo + 1) * 64 + dd);
    }

    const int qg = w * 16 + l16;         // lane's q (local to the 64-block)

    // per-tile body: write reg set to LDS, refill it from tile kt+2, compute
    auto body = [&](s8v& kr0, s8v& kr1, s8v& vv0, s8v& vv1, int kt) {
        __syncthreads();                 // all waves done reading prev sK/sVT
        *(s8v*)(sK  + r0 * LP + dd)        = kr0;
        *(s8v*)(sK  + (r0 + 32) * LP + dd) = kr1;
        *(s8v*)(sVT + r0 * LP + dd)        = vv0;
        *(s8v*)(sVT + (r0 + 32) * LP + dd) = vv1;
        if (kt + 2 < khi) {              // refill this set; flies 2 phases
            kr0 = *(const s8v*)(Kbase + (size_t)((kt + 2) * 64 + r0) * LDQ + dd);
            kr1 = *(const s8v*)(Kbase + (size_t)((kt + 2) * 64 + r0 + 32) * LDQ + dd);
            vv0 = *(const s8v*)(Vbase + (size_t)r0 * 2048 + (kt + 2) * 64 + dd);
            vv1 = *(const s8v*)(Vbase + (size_t)(r0 + 32) * 2048 + (kt + 2) * 64 + dd);
        }
        __syncthreads();                 // staging visible

        // swapped QK^T: sacc = K·Q^T -> lane holds S[k=nt*16+quad*4+r][q=l16]
        f4v sacc[4];
        __builtin_amdgcn_s_setprio(1);   // T5: favor compute wave vs staging
#pragma unroll
        for (int nt = 0; nt < 4; nt++) {
            sacc[nt] = vzero;
            s8v kf0 = *(const s8v*)(sK + (nt * 16 + l16) * LP + quad * 8);
            s8v kf1 = *(const s8v*)(sK + (nt * 16 + l16) * LP + 32 + quad * 8);
            sacc[nt] = __builtin_amdgcn_mfma_f32_16x16x32_bf16(kf0, qf[0], sacc[nt], 0, 0, 0);
            sacc[nt] = __builtin_amdgcn_mfma_f32_16x16x32_bf16(kf1, qf[1], sacc[nt], 0, 0, 0);
        }
        __builtin_amdgcn_s_setprio(0);

        // P = exp(S); truncate to bf16, lsum accumulates truncated value.
        // 4 consecutive-k values per nt -> one packed ds_write_b64 each.
        short* pp = sP[w];
        const bool diag = (kt == qt);
#pragma unroll
        for (int nt = 0; nt < 4; nt++) {
            unsigned pu[4];
#pragma unroll
            for (int r = 0; r < 4; r++) {
                float p = __expf(sacc[nt][r]);
                if (diag) {
                    int k = nt * 16 + quad * 4 + r;
                    if (k > qg) p = 0.0f;
                }
                union { float f; unsigned u; } c2; c2.f = p;
                c2.u &= 0xFFFF0000u;
                pu[r] = c2.u;
                lsum += c2.f;
            }
            s4v pk;
            pk[0] = (short)(pu[0] >> 16); pk[1] = (short)(pu[1] >> 16);
            pk[2] = (short)(pu[2] >> 16); pk[3] = (short)(pu[3] >> 16);
            *(s4v*)(pp + l16 * LP + nt * 16 + quad * 4) = pk;
        }
        // sP[w] is wave-private: no block barrier needed before PV reads

        s8v pf0 = *(const s8v*)(pp + l16 * LP + quad * 8);
        s8v pf1 = *(const s8v*)(pp + l16 * LP + 32 + quad * 8);
        __builtin_amdgcn_s_setprio(1);   // T5: PV cluster
#pragma unroll
        for (int dt = 0; dt < 4; dt++) {
            s8v vf0 = *(const s8v*)(sVT + (dt * 16 + l16) * LP + quad * 8);
            s8v vf1 = *(const s8v*)(sVT + (dt * 16 + l16) * LP + 32 + quad * 8);
            o[dt] = __builtin_amdgcn_mfma_f32_16x16x32_bf16(pf0, vf0, o[dt], 0, 0, 0);
            o[dt] = __builtin_amdgcn_mfma_f32_16x16x32_bf16(pf1, vf1, o[dt], 0, 0, 0);
        }
        __builtin_amdgcn_s_setprio(0);
    };

    for (int kt = klo; kt < khi; kt += 2) {
        body(ka0, ka1, va0, va1, kt);
        if (kt + 1 < khi)
            body(kb0, kb1, vb0, vb1, kt + 1);
    }

    // reduce lsum over quad (lanes l16, l16+16, l16+32, l16+48)
    lsum += __shfl_xor(lsum, 16, 64);
    lsum += __shfl_xor(lsum, 32, 64);

    if (PARTS == 2) {
        short* ob = Opart + ((size_t)(part * 1024 + u)) * 4096;
#pragma unroll
        for (int dt = 0; dt < 4; dt++)
#pragma unroll
            for (int r = 0; r < 4; r++)
                ob[(w * 16 + quad * 4 + r) * 64 + dt * 16 + l16] = f2b(o[dt][r]);
        if (lane < 16)
            Lpart[(size_t)(part * 1024 + u) * 64 + w * 16 + lane] = lsum;
    } else {
        float rls[4];
#pragma unroll
        for (int r = 0; r < 4; r++)
            rls[r] = 1.0f / __shfl(lsum, quad * 4 + r, 64);
#pragma unroll
        for (int dt = 0; dt < 4; dt++)
#pragma unroll
            for (int r = 0; r < 4; r++) {
                int qrow = qt * 64 + w * 16 + quad * 4 + r;
                int d = dt * 16 + l16;
                y[((size_t)b * T + qrow) * 1024 + h * 64 + d] = f2b(o[dt][r] * rls[r]);
            }
    }
}

// ---------------------------------------------------------------------------
// Combine split-K partials: y = (O0 + O1) / (l0 + l1). 1024 blocks x 256.
// ---------------------------------------------------------------------------
__global__ __launch_bounds__(256) void attn_combine(
    const short* __restrict__ Opart,
    const float* __restrict__ Lpart,
    short* __restrict__ y)
{
    const int u  = blockIdx.x;           // u = bh*32 + qt
    const int bh = u >> 5, qt = u & 31;
    const int b = bh >> 4, h = bh & 15;
    const int t = threadIdx.x;
    const int q = t >> 2, dg = (t & 3) * 16;

    float l = Lpart[(size_t)u * 64 + q] + Lpart[(size_t)(1024 + u) * 64 + q];
    float rl = 1.0f / l;
    const short* p0 = Opart + (size_t)u * 4096 + q * 64 + dg;
    const short* p1 = Opart + (size_t)(1024 + u) * 4096 + q * 64 + dg;
    short* yo = y + ((size_t)b * 2048 + qt * 64 + q) * 1024 + h * 64 + dg;
#pragma unroll
    for (int hv = 0; hv < 2; hv++) {
        s8v a = *(const s8v*)(p0 + hv * 8);
        s8v c = *(const s8v*)(p1 + hv * 8);
        s8v r;
#pragma unroll
        for (int j = 0; j < 8; j++) r[j] = f2b((b2f(a[j]) + b2f(c[j])) * rl);
        *(s8v*)(yo + hv * 8) = r;
    }
}

// ---------------------------------------------------------------------------
extern "C" void kernel_launch(void* const* d_in, const int* in_sizes, int n_in,
                              void* d_out, int out_size, void* d_ws, size_t ws_size,
                              hipStream_t stream)
{
    char* p = (char*)d_ws;
    int*   flag = (int*)p;                 p += 16;
    short* qk   = (short*)p;               p += (size_t)4096 * 2048 * 2;
    short* vT   = (short*)p;               p += (size_t)32 * 64 * 2048 * 2;
    short* xb   = (short*)p;               p += (size_t)4096 * 1024 * 2;
    short* Web  = (short*)p;               p += (size_t)3072 * 1024 * 2;
    short* Wpb  = (short*)p;               p += (size_t)1024 * 1024 * 2;
    short* beb  = (short*)p;               p += 3072 * 2;
    short* bpb  = (short*)p;               p += 1024 * 2;
    short* Opart = (short*)p;              p += (size_t)2 * 1024 * 4096 * 2;
    float* Lpart = (float*)p;              p += (size_t)2 * 1024 * 64 * 4;
    short* y = xb;                         // xb dead after QKV GEMM
    const size_t need = (size_t)(p - (char*)d_ws);
    const bool split = (ws_size >= need);

    // convert (self-detecting dtype; publishes flag for proj epilogue)
    convert_bf16<<<dim3(4098), 256, 0, stream>>>(
        d_in[0], xb,  (size_t)4096 * 1024 / 8,
        d_in[1], Web, (size_t)3072 * 1024 / 8,
        d_in[2], beb, (size_t)3072 / 8,
        d_in[3], Wpb, (size_t)1024 * 1024 / 8,
        d_in[4], bpb, (size_t)1024 / 8,
        flag);

    // qkv = x @ We^T + be ; Q (prescaled 1/8), K -> qk ; V -> vT transposed
    // 128x128 tiles, 768 blocks = 3/CU, T1 XCD swizzle
    gemm_bt_bias<1, 128, 128, 3><<<dim3(3072 / 128, 4096 / 128), 256, 0, stream>>>(
        xb, Web, beb, qk, vT, 4096, 3072, 1024, 2048, flag, 0);

    if (split) {
        attn_flash<2><<<dim3(2048), 256, 0, stream>>>(qk, vT, nullptr, Opart, Lpart);
        attn_combine<<<dim3(1024), 256, 0, stream>>>(Opart, Lpart, y);
    } else {
        attn_flash<1><<<dim3(1024), 256, 0, stream>>>(qk, vT, y, nullptr, nullptr);
    }

    // out = y @ Wp^T + bp ; 128x64 tiles, 512 blocks, T1 XCD swizzle
    gemm_bt_bias<0, 128, 64, 2><<<dim3(1024 / 64, 4096 / 128), 256, 0, stream>>>(
        y, Wpb, bpb, d_out, nullptr, 4096, 1024, 1024, 1024, flag, 1);
}